// Round 4
// baseline (69.792 us; speedup 1.0000x reference)
//
#include <hip/hip_runtime.h>

// DRR via exact Siddon line integral, incremental traversal.
// Locality-first mapping: block = 16x16 detector tile, wave = 8x8 pixel patch,
// alpha range split across blocks (32 depth chunks), atomicAdd combine.
static constexpr float F_SDD = 1020.0f;
static constexpr int   DH = 160, DW = 160;       // detector H, W
static constexpr float DELX = 2.5f, DELY = 2.5f;
static constexpr int   VOL = 256;                // volume is VOL^3
static constexpr int   NRAY = DH * DW;
static constexpr int   TILES_X = DW / 16;        // 10
static constexpr int   TILES_Y = DH / 16;        // 10
static constexpr int   NTILE = TILES_X * TILES_Y;// 100
static constexpr int   CHUNKS = 32;              // alpha chunks per ray (across blocks)
static constexpr float EPS = 1e-8f;

__device__ __forceinline__ void axis_init(float s, float sd, float a0,
                                          float& anext, float& da) {
    if (fabsf(sd) < EPS) { anext = 3.0e38f; da = 0.0f; return; }
    float p = s + a0 * sd;
    float k = (sd > 0.0f) ? (floorf(p) + 1.0f) : (ceilf(p) - 1.0f);
    anext = (k - s) / sd;
    da = 1.0f / fabsf(sd);
}

extern "C" __global__ void zero_out_kernel(float* __restrict__ out, int n) {
    int i = blockIdx.x * blockDim.x + threadIdx.x;
    if (i < n) out[i] = 0.0f;
}

extern "C" __global__ void __launch_bounds__(256)
drr_siddon_kernel(const float* __restrict__ density,
                  const float* __restrict__ pose,   // [4][4] row-major
                  const float* __restrict__ ainv,   // [4][4] row-major
                  float* __restrict__ out)          // [NRAY]
{
    // chunk fast-varying so consecutive blocks (-> different XCDs) own
    // different depth slabs of the volume.
    int chunk = blockIdx.x & (CHUNKS - 1);
    int tile  = blockIdx.x >> 5;                    // CHUNKS == 32
    int tx = tile % TILES_X, ty = tile / TILES_X;

    // wave = 8x8 pixel patch: lanes of one wave are NEIGHBORING rays at the
    // SAME alpha chunk -> coherent gathers (i2 is the 4B-stride axis).
    int lane = threadIdx.x & 63;
    int w    = threadIdx.x >> 6;
    int px_l = (lane & 7) | ((w & 1) << 3);         // 0..15
    int py_l = (lane >> 3) | ((w >> 1) << 3);       // 0..15
    int px = tx * 16 + px_l;
    int py = ty * 16 + py_l;
    int ray = py * DW + px;

    // Detector-plane target in camera frame (source at origin).
    float xs = ((float)px - (DW - 1) * 0.5f) * DELX;
    float ys = ((float)py - (DH - 1) * 0.5f) * DELY;

    // pose: rows of [R | t]
    float R00 = pose[0], R01 = pose[1], R02 = pose[2],  t0 = pose[3];
    float R10 = pose[4], R11 = pose[5], R12 = pose[6],  t1 = pose[7];
    float R20 = pose[8], R21 = pose[9], R22 = pose[10], t2 = pose[11];

    float sw0 = t0, sw1 = t1, sw2 = t2;                       // src_w = R*0 + t
    float tw0 = R00 * xs + R01 * ys + R02 * F_SDD + t0;
    float tw1 = R10 * xs + R11 * ys + R12 * F_SDD + t1;
    float tw2 = R20 * xs + R21 * ys + R22 * F_SDD + t2;

    float dw0 = tw0 - sw0, dw1 = tw1 - sw1, dw2 = tw2 - sw2;
    float raylen = sqrtf(dw0 * dw0 + dw1 * dw1 + dw2 * dw2);

    // world -> voxel
    float A00 = ainv[0], A01 = ainv[1], A02 = ainv[2],  A03 = ainv[3];
    float A10 = ainv[4], A11 = ainv[5], A12 = ainv[6],  A13 = ainv[7];
    float A20 = ainv[8], A21 = ainv[9], A22 = ainv[10], A23 = ainv[11];

    float s0 = A00 * sw0 + A01 * sw1 + A02 * sw2 + A03;
    float s1 = A10 * sw0 + A11 * sw1 + A12 * sw2 + A13;
    float s2 = A20 * sw0 + A21 * sw1 + A22 * sw2 + A23;
    float g0 = A00 * tw0 + A01 * tw1 + A02 * tw2 + A03;
    float g1 = A10 * tw0 + A11 * tw1 + A12 * tw2 + A13;
    float g2 = A20 * tw0 + A21 * tw1 + A22 * tw2 + A23;

    float sd0 = g0 - s0, sd1 = g1 - s1, sd2 = g2 - s2;
    float e0 = (fabsf(sd0) < EPS) ? EPS : sd0;
    float e1 = (fabsf(sd1) < EPS) ? EPS : sd1;
    float e2 = (fabsf(sd2) < EPS) ? EPS : sd2;

    // bbox entry/exit in alpha, clamped to the [0,1] segment
    float lo0 = (0.0f - s0) / e0, hi0 = ((float)VOL - s0) / e0;
    float lo1 = (0.0f - s1) / e1, hi1 = ((float)VOL - s1) / e1;
    float lo2 = (0.0f - s2) / e2, hi2 = ((float)VOL - s2) / e2;
    float amin = fmaxf(fmaxf(fminf(lo0, hi0), fminf(lo1, hi1)), fminf(lo2, hi2));
    amin = fmaxf(amin, 0.0f);
    float amax = fminf(fminf(fmaxf(lo0, hi0), fmaxf(lo1, hi1)), fmaxf(lo2, hi2));
    amax = fminf(amax, 1.0f);
    amax = fmaxf(amax, amin);

    // this block's exact alpha sub-range (identical float math in every block
    // of the same ray -> exact cover, no gaps/overlap)
    float arange  = amax - amin;
    float a_start = amin + arange * ((float)chunk * (1.0f / CHUNKS));
    float a_end   = (chunk == CHUNKS - 1) ? amax
                    : amin + arange * ((float)(chunk + 1) * (1.0f / CHUNKS));

    float ax0, ax1, ax2, da0, da1, da2;
    axis_init(s0, sd0, a_start, ax0, da0);
    axis_init(s1, sd1, a_start, ax1, da1);
    axis_init(s2, sd2, a_start, ax2, da2);

    // 2-deep software pipeline: issue this segment's gather, retire the
    // previous segment's FMA.
    float acc = 0.0f;
    float alpha = a_start;
    float pend_v = 0.0f, pend_seg = 0.0f;
    while (alpha < a_end) {
        float anext = fminf(fminf(ax0, ax1), ax2);
        float astop = fminf(anext, a_end);
        float amid = 0.5f * (alpha + astop);
        int i0 = (int)floorf(s0 + amid * sd0);
        int i1 = (int)floorf(s1 + amid * sd1);
        int i2 = (int)floorf(s2 + amid * sd2);
        i0 = min(max(i0, 0), VOL - 1);
        i1 = min(max(i1, 0), VOL - 1);
        i2 = min(max(i2, 0), VOL - 1);
        float v = density[(i0 << 16) + (i1 << 8) + i2];   // issue load
        float seg = astop - alpha;
        acc += pend_v * pend_seg;                         // retire previous
        pend_v = v; pend_seg = seg;
        if (ax0 == anext) ax0 += da0;
        if (ax1 == anext) ax1 += da1;
        if (ax2 == anext) ax2 += da2;
        alpha = anext;
    }
    acc += pend_v * pend_seg;                             // flush pipeline

    atomicAdd(&out[ray], acc * raylen);
}

extern "C" void kernel_launch(void* const* d_in, const int* in_sizes, int n_in,
                              void* d_out, int out_size, void* d_ws, size_t ws_size,
                              hipStream_t stream) {
    const float* density = (const float*)d_in[0];
    const float* pose    = (const float*)d_in[1];   // [1,4,4]
    const float* ainv    = (const float*)d_in[2];   // [4,4]
    float* out = (float*)d_out;                     // [1,1,160,160] flat

    hipLaunchKernelGGL(zero_out_kernel, dim3((NRAY + 255) / 256), dim3(256), 0,
                       stream, out, NRAY);

    dim3 block(256);
    dim3 grid(NTILE * CHUNKS);                      // 3200 blocks
    hipLaunchKernelGGL(drr_siddon_kernel, grid, block, 0, stream,
                       density, pose, ainv, out);
}

// Round 5
// 41.917 us; speedup vs baseline: 1.6650x; 1.6650x over previous
//
#include <hip/hip_runtime.h>

// DRR via exact Siddon line integral, incremental traversal.
// Block = 16x16 detector tile x one depth chunk (1024 threads: 4 alpha
// sub-ranges per ray). CHUNKS=8 with chunk fast-varying keeps depth slab k
// pinned to XCD k's L2 (round-robin dispatch) -> minimal refetch traffic.
static constexpr float F_SDD = 1020.0f;
static constexpr int   DH = 160, DW = 160;       // detector H, W
static constexpr float DELX = 2.5f, DELY = 2.5f;
static constexpr int   VOL = 256;                // volume is VOL^3
static constexpr int   NRAY = DH * DW;
static constexpr int   TILES_X = DW / 16;        // 10
static constexpr int   TILES_Y = DH / 16;        // 10
static constexpr int   NTILE = TILES_X * TILES_Y;// 100
static constexpr int   CHUNKS = 8;               // depth chunks (== XCD count)
static constexpr int   SUBS = 4;                 // intra-block split per ray
static constexpr float EPS = 1e-8f;

__device__ __forceinline__ void axis_init(float s, float sd, float a0,
                                          float& anext, float& da) {
    if (fabsf(sd) < EPS) { anext = 3.0e38f; da = 0.0f; return; }
    float p = s + a0 * sd;
    float k = (sd > 0.0f) ? (floorf(p) + 1.0f) : (ceilf(p) - 1.0f);
    anext = (k - s) / sd;
    da = 1.0f / fabsf(sd);
}

extern "C" __global__ void zero_out_kernel(float* __restrict__ out, int n) {
    int i = blockIdx.x * blockDim.x + threadIdx.x;
    if (i < n) out[i] = 0.0f;
}

extern "C" __global__ void __launch_bounds__(1024)
drr_siddon_kernel(const float* __restrict__ density,
                  const float* __restrict__ pose,   // [4][4] row-major
                  const float* __restrict__ ainv,   // [4][4] row-major
                  float* __restrict__ out)          // [NRAY]
{
    __shared__ float red[1024];

    int chunk = blockIdx.x & (CHUNKS - 1);          // fast-varying -> XCD id
    int tile  = blockIdx.x >> 3;                    // CHUNKS == 8
    int tx = tile % TILES_X, ty = tile / TILES_X;

    int tid  = threadIdx.x;
    int sub  = tid >> 8;                            // 0..3 (changes every 4 waves)
    int t256 = tid & 255;

    // wave = 8x8 pixel patch at one alpha sub-range: lanes are NEIGHBORING
    // rays at the SAME alpha -> coherent gathers (i2 is the 4B-stride axis).
    int lane = t256 & 63;
    int w    = t256 >> 6;
    int px_l = (lane & 7) | ((w & 1) << 3);         // 0..15
    int py_l = (lane >> 3) | ((w >> 1) << 3);       // 0..15
    int px = tx * 16 + px_l;
    int py = ty * 16 + py_l;
    int ray = py * DW + px;

    // Detector-plane target in camera frame (source at origin).
    float xs = ((float)px - (DW - 1) * 0.5f) * DELX;
    float ys = ((float)py - (DH - 1) * 0.5f) * DELY;

    // pose: rows of [R | t]
    float R00 = pose[0], R01 = pose[1], R02 = pose[2],  t0 = pose[3];
    float R10 = pose[4], R11 = pose[5], R12 = pose[6],  t1 = pose[7];
    float R20 = pose[8], R21 = pose[9], R22 = pose[10], t2 = pose[11];

    float sw0 = t0, sw1 = t1, sw2 = t2;                       // src_w = R*0 + t
    float tw0 = R00 * xs + R01 * ys + R02 * F_SDD + t0;
    float tw1 = R10 * xs + R11 * ys + R12 * F_SDD + t1;
    float tw2 = R20 * xs + R21 * ys + R22 * F_SDD + t2;

    float dw0 = tw0 - sw0, dw1 = tw1 - sw1, dw2 = tw2 - sw2;
    float raylen = sqrtf(dw0 * dw0 + dw1 * dw1 + dw2 * dw2);

    // world -> voxel
    float A00 = ainv[0], A01 = ainv[1], A02 = ainv[2],  A03 = ainv[3];
    float A10 = ainv[4], A11 = ainv[5], A12 = ainv[6],  A13 = ainv[7];
    float A20 = ainv[8], A21 = ainv[9], A22 = ainv[10], A23 = ainv[11];

    float s0 = A00 * sw0 + A01 * sw1 + A02 * sw2 + A03;
    float s1 = A10 * sw0 + A11 * sw1 + A12 * sw2 + A13;
    float s2 = A20 * sw0 + A21 * sw1 + A22 * sw2 + A23;
    float g0 = A00 * tw0 + A01 * tw1 + A02 * tw2 + A03;
    float g1 = A10 * tw0 + A11 * tw1 + A12 * tw2 + A13;
    float g2 = A20 * tw0 + A21 * tw1 + A22 * tw2 + A23;

    float sd0 = g0 - s0, sd1 = g1 - s1, sd2 = g2 - s2;
    float e0 = (fabsf(sd0) < EPS) ? EPS : sd0;
    float e1 = (fabsf(sd1) < EPS) ? EPS : sd1;
    float e2 = (fabsf(sd2) < EPS) ? EPS : sd2;

    // bbox entry/exit in alpha, clamped to the [0,1] segment
    float lo0 = (0.0f - s0) / e0, hi0 = ((float)VOL - s0) / e0;
    float lo1 = (0.0f - s1) / e1, hi1 = ((float)VOL - s1) / e1;
    float lo2 = (0.0f - s2) / e2, hi2 = ((float)VOL - s2) / e2;
    float amin = fmaxf(fmaxf(fminf(lo0, hi0), fminf(lo1, hi1)), fminf(lo2, hi2));
    amin = fmaxf(amin, 0.0f);
    float amax = fminf(fminf(fmaxf(lo0, hi0), fmaxf(lo1, hi1)), fmaxf(lo2, hi2));
    amax = fminf(amax, 1.0f);
    amax = fmaxf(amax, amin);

    // this block's chunk sub-range (identical float math in every block of the
    // same ray -> exact cover across blocks), then this thread's exact quarter
    // (identical math within the block -> exact cover across subs).
    float arange  = amax - amin;
    float c_start = amin + arange * ((float)chunk * (1.0f / CHUNKS));
    float c_end   = (chunk == CHUNKS - 1) ? amax
                    : amin + arange * ((float)(chunk + 1) * (1.0f / CHUNKS));
    float crange  = c_end - c_start;
    float a_start = c_start + crange * ((float)sub * (1.0f / SUBS));
    float a_end   = (sub == SUBS - 1) ? c_end
                    : c_start + crange * ((float)(sub + 1) * (1.0f / SUBS));

    float ax0, ax1, ax2, da0, da1, da2;
    axis_init(s0, sd0, a_start, ax0, da0);
    axis_init(s1, sd1, a_start, ax1, da1);
    axis_init(s2, sd2, a_start, ax2, da2);

    // 2-deep software pipeline: issue this segment's gather, retire the
    // previous segment's FMA.
    float acc = 0.0f;
    float alpha = a_start;
    float pend_v = 0.0f, pend_seg = 0.0f;
    while (alpha < a_end) {
        float anext = fminf(fminf(ax0, ax1), ax2);
        float astop = fminf(anext, a_end);
        float amid = 0.5f * (alpha + astop);
        int i0 = (int)floorf(s0 + amid * sd0);
        int i1 = (int)floorf(s1 + amid * sd1);
        int i2 = (int)floorf(s2 + amid * sd2);
        i0 = min(max(i0, 0), VOL - 1);
        i1 = min(max(i1, 0), VOL - 1);
        i2 = min(max(i2, 0), VOL - 1);
        float v = density[(i0 << 16) + (i1 << 8) + i2];   // issue load
        float seg = astop - alpha;
        acc += pend_v * pend_seg;                         // retire previous
        pend_v = v; pend_seg = seg;
        if (ax0 == anext) ax0 += da0;
        if (ax1 == anext) ax1 += da1;
        if (ax2 == anext) ax2 += da2;
        alpha = anext;
    }
    acc += pend_v * pend_seg;                             // flush pipeline

    // combine the 4 sub-range partials for each ray in LDS, then one atomic.
    red[tid] = acc;
    __syncthreads();
    if (tid < 256) {
        float total = red[tid] + red[tid + 256] + red[tid + 512] + red[tid + 768];
        atomicAdd(&out[ray], total * raylen);
    }
}

extern "C" void kernel_launch(void* const* d_in, const int* in_sizes, int n_in,
                              void* d_out, int out_size, void* d_ws, size_t ws_size,
                              hipStream_t stream) {
    const float* density = (const float*)d_in[0];
    const float* pose    = (const float*)d_in[1];   // [1,4,4]
    const float* ainv    = (const float*)d_in[2];   // [4,4]
    float* out = (float*)d_out;                     // [1,1,160,160] flat

    hipLaunchKernelGGL(zero_out_kernel, dim3((NRAY + 255) / 256), dim3(256), 0,
                       stream, out, NRAY);

    dim3 block(1024);
    dim3 grid(NTILE * CHUNKS);                      // 800 blocks
    hipLaunchKernelGGL(drr_siddon_kernel, grid, block, 0, stream,
                       density, pose, ainv, out);
}